// Round 6
// baseline (4837.894 us; speedup 1.0000x reference)
//
#include <hip/hip_runtime.h>
#include <hip/hip_fp16.h>
#include <math.h>

#define DD 128
#define TAU2 2.0f
#define EPSV 1e-12f

#define CSHIFT 13            // 8192 rows per chunk
#define CROWS  (1 << CSHIFT)
#define IPC    256           // prep items per chunk
#define RPI    32            // rows per item (IPC*RPI == CROWS)

// Packet layout (16 B): packet j (j=0..31) of a row covers cols 4j..4j+3:
//   { half2(ev0,ev1), half2(ev2,ev3), half2(ar0,ar1), half2(ar2,ar3) }
// Row stride = 256 ushorts = 512 B. tab indexed by GLOBAL exemplar row.

// ---------------------------------------------------------------------------
// Fused producer-consumer kernel. One block per output row b.
// ctrl[0] = prep ticket; ctrl[16+c] = done-count for chunk c (== IPC when
// chunk fully prepped). Any block claims prep items (work-stealing) while
// the chunk its gather needs is not ready -> deadlock-free under ANY
// dispatch order; prep (HBM) overlaps gather (L3->L2 fill) dynamically.
// ---------------------------------------------------------------------------
__global__ __launch_bounds__(256) void fused_kernel(
    const float* __restrict__ sq_dists,   // [B,K]
    const int*   __restrict__ labels,     // [B,K]
    const float* __restrict__ log_ev,     // [E,D]
    const float* __restrict__ log_cen,    // [E,D]
    const float* __restrict__ log_be,     // [D]
    const float* __restrict__ log_bc,     // [D]
    unsigned short* __restrict__ tab,     // [E][256] packed fp16
    unsigned int* __restrict__ ctrl,
    float* __restrict__ out,              // [B,D]
    int K, long long E, int nchunk, unsigned total_items) {

    __shared__ float w_s[128];
    __shared__ int   lab_s[128];
    __shared__ short ord_s[128];
    __shared__ int   start_s[33];
    __shared__ float bev_s[DD];
    __shared__ float bar_s[DD];
    __shared__ float rn[8][DD];
    __shared__ float rd[8][DD];
    __shared__ unsigned sh_ready, sh_item;

    int b = blockIdx.x;
    int tid = threadIdx.x;
    int wid = tid >> 6;
    int lane = tid & 63;
    int j = lane & 31;
    int h = lane >> 5;
    int part = wid * 2 + h;          // halfwave id 0..7

    // ---- stage weights + labels ----
    if (tid < K) {
        float sqd = sq_dists[(size_t)b * K + tid];
        w_s[tid]  = (sqd <= TAU2) ? __expf(-sqd) : 0.0f;
        lab_s[tid] = labels[(size_t)b * K + tid];
    }
    // ---- baseline row into LDS (lanes 0..31 of wave 0) ----
    if (tid < 32) {
        float4 lb = *(const float4*)(log_be + 4 * tid);
        float4 lc = *(const float4*)(log_bc + 4 * tid);
        float e0 = __expf(lb.x), e1 = __expf(lb.y), e2 = __expf(lb.z), e3 = __expf(lb.w);
        float s0 = e0 + __expf(lc.x), s1 = e1 + __expf(lc.y);
        float s2 = e2 + __expf(lc.z), s3 = e3 + __expf(lc.w);
        float t = s0 + s1 + s2 + s3;
        #pragma unroll
        for (int off = 1; off < 32; off <<= 1) {
            float v = __shfl_down(t, off, 64);
            t += (tid + off < 32) ? v : 0.0f;
        }
        *(float4*)&bev_s[4 * tid] = make_float4(e0, e1, e2, e3);
        *(float4*)&bar_s[4 * tid] = make_float4(t, t - s0, t - s0 - s1, t - s0 - s1 - s2);
    }
    __syncthreads();

    // ---- deterministic stable bucket sort of the K labels by chunk ----
    if (tid <= nchunk) start_s[tid] = 0;
    __syncthreads();
    if (tid < nchunk) {
        int c = 0;
        for (int k = 0; k < K; ++k) c += ((lab_s[k] >> CSHIFT) == tid);
        start_s[tid + 1] = c;
    }
    __syncthreads();
    if (tid == 0)
        for (int c = 1; c <= nchunk; ++c) start_s[c] += start_s[c - 1];
    __syncthreads();
    if (tid < K) {
        int bk = lab_s[tid] >> CSHIFT;
        int pos = 0;
        for (int k2 = 0; k2 < tid; ++k2) pos += ((lab_s[k2] >> CSHIFT) == bk);
        ord_s[start_s[bk] + pos] = (short)tid;
    }
    __syncthreads();

    unsigned int* ticket = ctrl;
    unsigned int* done   = ctrl + 16;
    const unsigned short* jbase = tab + (size_t)j * 8;

    float n0 = 0.f, n1 = 0.f, n2 = 0.f, n3 = 0.f;
    float d0 = 0.f, d1 = 0.f, d2 = 0.f, d3 = 0.f;

    for (int c = 0; c < nchunk; ++c) {
        // ---- wait for chunk c; steal prep work while waiting ----
        int guard = 0;
        while (true) {
            if (tid == 0) {
                unsigned v = __hip_atomic_load(&done[c], __ATOMIC_ACQUIRE,
                                               __HIP_MEMORY_SCOPE_AGENT);
                if (v >= IPC) sh_ready = 1;
                else {
                    sh_ready = 0;
                    sh_item = __hip_atomic_fetch_add(ticket, 1u, __ATOMIC_RELAXED,
                                                     __HIP_MEMORY_SCOPE_AGENT);
                }
            }
            __syncthreads();
            unsigned rdy = sh_ready;
            unsigned it  = sh_item;
            __syncthreads();
            if (rdy) break;
            if (it < total_items) {
                // ---- prep item: 32 rows, 4 per halfwave ----
                unsigned ct = it >> 8;
                long long ibase = ((long long)ct << CSHIFT) + (long long)(it & 255) * RPI;
                #pragma unroll
                for (int r = 0; r < 4; ++r) {
                    long long row = ibase + (long long)part * 4 + r;
                    if (row < E) {
                        size_t idx = (size_t)row * DD + 4 * j;
                        float4 le = *(const float4*)(log_ev + idx);
                        float4 lc = *(const float4*)(log_cen + idx);
                        float e0 = __expf(le.x), e1 = __expf(le.y);
                        float e2 = __expf(le.z), e3 = __expf(le.w);
                        float s0 = e0 + __expf(lc.x), s1 = e1 + __expf(lc.y);
                        float s2 = e2 + __expf(lc.z), s3 = e3 + __expf(lc.w);
                        float t = s0 + s1 + s2 + s3;
                        #pragma unroll
                        for (int off = 1; off < 32; off <<= 1) {
                            float v = __shfl_down(t, off, 64);
                            t += (j + off < 32) ? v : 0.0f;
                        }
                        __half2 ep0 = __floats2half2_rn(e0, e1);
                        __half2 ep1 = __floats2half2_rn(e2, e3);
                        __half2 ap0 = __floats2half2_rn(t, t - s0);
                        __half2 ap1 = __floats2half2_rn(t - s0 - s1, t - s0 - s1 - s2);
                        uint4 pkt;
                        pkt.x = *(unsigned int*)&ep0;
                        pkt.y = *(unsigned int*)&ep1;
                        pkt.z = *(unsigned int*)&ap0;
                        pkt.w = *(unsigned int*)&ap1;
                        *(uint4*)(tab + (size_t)row * 256 + (size_t)j * 8) = pkt;
                    }
                }
                __threadfence();          // flush this thread's table writes
                __syncthreads();          // all writers flushed
                if (tid == 0)
                    __hip_atomic_fetch_add(&done[ct], 1u, __ATOMIC_RELEASE,
                                           __HIP_MEMORY_SCOPE_AGENT);
            } else {
                __builtin_amdgcn_s_sleep(8);
            }
            __syncthreads();
            if (++guard > (1 << 23)) break;   // safety valve: fail visibly, never hang
        }
        __threadfence();   // invalidate caches before reading chunk's rows

        // ---- gather this block's neighbors in chunk c ----
        for (int i = start_s[c] + part; i < start_s[c + 1]; i += 8) {
            int k = ord_s[i];
            int l = lab_s[k];
            float wk = w_s[k];
            uint4 pkt = *(const uint4*)(jbase + (size_t)l * 256);
            float2 e01 = __half22float2(*(const __half2*)&pkt.x);
            float2 e23 = __half22float2(*(const __half2*)&pkt.y);
            float2 a01 = __half22float2(*(const __half2*)&pkt.z);
            float2 a23 = __half22float2(*(const __half2*)&pkt.w);
            n0 = fmaf(wk, e01.x, n0); n1 = fmaf(wk, e01.y, n1);
            n2 = fmaf(wk, e23.x, n2); n3 = fmaf(wk, e23.y, n3);
            d0 = fmaf(wk, a01.x, d0); d1 = fmaf(wk, a01.y, d1);
            d2 = fmaf(wk, a23.x, d2); d3 = fmaf(wk, a23.y, d3);
        }
    }

    // ---- reduce 8 halfwave partials + fused finalize ----
    *(float4*)&rn[part][4 * j] = make_float4(n0, n1, n2, n3);
    *(float4*)&rd[part][4 * j] = make_float4(d0, d1, d2, d3);
    __syncthreads();

    if (tid < DD) {
        float n  = rn[0][tid] + rn[1][tid] + rn[2][tid] + rn[3][tid]
                 + rn[4][tid] + rn[5][tid] + rn[6][tid] + rn[7][tid];
        float dn = rd[0][tid] + rd[1][tid] + rd[2][tid] + rd[3][tid]
                 + rd[4][tid] + rd[5][tid] + rd[6][tid] + rd[7][tid];
        n  += bev_s[tid];
        dn += bar_s[tid] + EPSV;
        float r = n / dn;
        out[(size_t)b * DD + tid] = fminf(fmaxf(r, EPSV), 1.0f - EPSV);
    }
}

// ===========================================================================
// Fallback path (ws too small or too many chunks): R4's separate kernels.
// ===========================================================================
__global__ __launch_bounds__(256) void prep_kernel(
    const float* __restrict__ log_ev, const float* __restrict__ log_cen,
    const float* __restrict__ log_be, const float* __restrict__ log_bc,
    unsigned short* __restrict__ tab, float* __restrict__ base_ev,
    float* __restrict__ base_ar, long long c0, long long rows, int do_base) {
    int tid = threadIdx.x;
    int lane = tid & 63;
    int j = lane & 31;
    int h = lane >> 5;
    if (do_base && blockIdx.x == 0 && tid < 32) {
        float4 lb = *(const float4*)(log_be + 4 * j);
        float4 lc = *(const float4*)(log_bc + 4 * j);
        float e0 = __expf(lb.x), e1 = __expf(lb.y), e2 = __expf(lb.z), e3 = __expf(lb.w);
        float s0 = e0 + __expf(lc.x), s1 = e1 + __expf(lc.y);
        float s2 = e2 + __expf(lc.z), s3 = e3 + __expf(lc.w);
        float t = s0 + s1 + s2 + s3;
        #pragma unroll
        for (int off = 1; off < 32; off <<= 1) {
            float v = __shfl_down(t, off, 64);
            t += (j + off < 32) ? v : 0.0f;
        }
        *(float4*)(base_ev + 4 * j) = make_float4(e0, e1, e2, e3);
        *(float4*)(base_ar + 4 * j) = make_float4(t, t - s0, t - s0 - s1, t - s0 - s1 - s2);
    }
    long long g = (((long long)blockIdx.x * blockDim.x + tid) >> 6) * 2 + h;
    long long ng = (((long long)gridDim.x * blockDim.x) >> 6) * 2;
    for (long long row = g; row < rows; row += ng) {
        long long e = row + c0;
        size_t idx = (size_t)e * DD + 4 * j;
        float4 le = *(const float4*)(log_ev + idx);
        float4 lc = *(const float4*)(log_cen + idx);
        float e0 = __expf(le.x), e1 = __expf(le.y), e2 = __expf(le.z), e3 = __expf(le.w);
        float s0 = e0 + __expf(lc.x), s1 = e1 + __expf(lc.y);
        float s2 = e2 + __expf(lc.z), s3 = e3 + __expf(lc.w);
        float t = s0 + s1 + s2 + s3;
        #pragma unroll
        for (int off = 1; off < 32; off <<= 1) {
            float v = __shfl_down(t, off, 64);
            t += (j + off < 32) ? v : 0.0f;
        }
        __half2 ep0 = __floats2half2_rn(e0, e1);
        __half2 ep1 = __floats2half2_rn(e2, e3);
        __half2 ap0 = __floats2half2_rn(t, t - s0);
        __half2 ap1 = __floats2half2_rn(t - s0 - s1, t - s0 - s1 - s2);
        uint4 pkt;
        pkt.x = *(unsigned int*)&ep0;
        pkt.y = *(unsigned int*)&ep1;
        pkt.z = *(unsigned int*)&ap0;
        pkt.w = *(unsigned int*)&ap1;
        *(uint4*)(tab + (size_t)row * 256 + (size_t)j * 8) = pkt;
    }
}

__global__ __launch_bounds__(256) void gather_kernel(
    const float* __restrict__ sq_dists, const int* __restrict__ labels,
    const unsigned short* __restrict__ tab, const float* __restrict__ base_ev,
    const float* __restrict__ base_ar, float* __restrict__ acc_num,
    float* __restrict__ acc_den, float* __restrict__ out,
    int K, int c0, int c1, int fused) {
    __shared__ float w_s[128];
    __shared__ int   lab_s[128];
    __shared__ float rn[8][DD];
    __shared__ float rd[8][DD];
    int b = blockIdx.x;
    int tid = threadIdx.x;
    if (tid < K) {
        float sqd = sq_dists[(size_t)b * K + tid];
        w_s[tid]  = (sqd <= TAU2) ? __expf(-sqd) : 0.0f;
        lab_s[tid] = labels[(size_t)b * K + tid];
    }
    __syncthreads();
    int wid = tid >> 6, lane = tid & 63, j = lane & 31, h = lane >> 5;
    const unsigned short* jbase = tab + (size_t)j * 8;
    float n0 = 0.f, n1 = 0.f, n2 = 0.f, n3 = 0.f;
    float d0 = 0.f, d1 = 0.f, d2 = 0.f, d3 = 0.f;
    int kpw = (K + 3) >> 2;
    for (int kk = h; kk < kpw; kk += 2) {
        int k = wid * kpw + kk;
        if (k >= K) break;
        int l = lab_s[k];
        if (l >= c0 && l < c1) {
            float wk = w_s[k];
            uint4 pkt = *(const uint4*)(jbase + (size_t)(l - c0) * 256);
            float2 e01 = __half22float2(*(const __half2*)&pkt.x);
            float2 e23 = __half22float2(*(const __half2*)&pkt.y);
            float2 a01 = __half22float2(*(const __half2*)&pkt.z);
            float2 a23 = __half22float2(*(const __half2*)&pkt.w);
            n0 = fmaf(wk, e01.x, n0); n1 = fmaf(wk, e01.y, n1);
            n2 = fmaf(wk, e23.x, n2); n3 = fmaf(wk, e23.y, n3);
            d0 = fmaf(wk, a01.x, d0); d1 = fmaf(wk, a01.y, d1);
            d2 = fmaf(wk, a23.x, d2); d3 = fmaf(wk, a23.y, d3);
        }
    }
    int part = wid * 2 + h;
    *(float4*)&rn[part][4 * j] = make_float4(n0, n1, n2, n3);
    *(float4*)&rd[part][4 * j] = make_float4(d0, d1, d2, d3);
    __syncthreads();
    if (tid < DD) {
        float n  = rn[0][tid] + rn[1][tid] + rn[2][tid] + rn[3][tid]
                 + rn[4][tid] + rn[5][tid] + rn[6][tid] + rn[7][tid];
        float dn = rd[0][tid] + rd[1][tid] + rd[2][tid] + rd[3][tid]
                 + rd[4][tid] + rd[5][tid] + rd[6][tid] + rd[7][tid];
        size_t o = (size_t)b * DD + tid;
        if (fused) {
            n  += base_ev[tid];
            dn += base_ar[tid] + EPSV;
            float r = n / dn;
            out[o] = fminf(fmaxf(r, EPSV), 1.0f - EPSV);
        } else {
            acc_num[o] += n;
            acc_den[o] += dn;
        }
    }
}

__global__ void finalize_kernel(const float* __restrict__ acc_num,
                                const float* __restrict__ acc_den,
                                const float* __restrict__ base_ev,
                                const float* __restrict__ base_ar,
                                float* __restrict__ out, int total) {
    int i = blockIdx.x * blockDim.x + threadIdx.x;
    if (i >= total) return;
    int d = i & (DD - 1);
    float n  = acc_num[i] + base_ev[d];
    float dn = acc_den[i] + base_ar[d] + EPSV;
    float r = n / dn;
    r = fminf(fmaxf(r, EPSV), 1.0f - EPSV);
    out[i] = r;
}

extern "C" void kernel_launch(void* const* d_in, const int* in_sizes, int n_in,
                              void* d_out, int out_size, void* d_ws, size_t ws_size,
                              hipStream_t stream) {
    const float* sq_dists = (const float*)d_in[0];
    const float* log_ev   = (const float*)d_in[1];
    const float* log_cen  = (const float*)d_in[2];
    const float* log_be   = (const float*)d_in[3];
    const float* log_bc   = (const float*)d_in[4];
    const int*   labels   = (const int*)d_in[5];
    float* out = (float*)d_out;

    const int Dv = in_sizes[3];                        // 128
    const long long E = (long long)in_sizes[1] / Dv;   // 100000
    const int B = out_size / Dv;                       // 4096
    const int K = in_sizes[0] / B;                     // 128

    // ws layout (floats): [ctrl 64][base_ev 128][base_ar 128][acc 2*B*D][tab ...]
    float* ws = (float*)d_ws;
    unsigned int* ctrl = (unsigned int*)ws;
    float* base_ev = ws + 64;
    float* base_ar = base_ev + Dv;
    float* acc_num = base_ar + Dv;
    float* acc_den = acc_num + (size_t)B * Dv;
    size_t head_floats = 64 + 2 * (size_t)Dv + 2 * (size_t)B * Dv;
    unsigned short* tab = (unsigned short*)(ws + head_floats);

    size_t head_bytes = head_floats * sizeof(float);
    size_t tab_bytes = (size_t)E * 2 * Dv * sizeof(unsigned short);
    int nchunk = (int)((E + CROWS - 1) >> CSHIFT);

    bool can_fuse = (K == 128) && (Dv == DD) && (nchunk <= 16) &&
                    (ws_size >= head_bytes + tab_bytes);

    if (can_fuse) {
        hipMemsetAsync(ctrl, 0, 256, stream);
        fused_kernel<<<B, 256, 0, stream>>>(sq_dists, labels, log_ev, log_cen,
                                            log_be, log_bc, tab, ctrl, out,
                                            K, E, nchunk,
                                            (unsigned)(nchunk * IPC));
        return;
    }

    // ---- fallback: chunked prep+gather (R4 path) ----
    long long cap = 0;
    if (ws_size > head_bytes)
        cap = (long long)((ws_size - head_bytes) / (2 * (size_t)Dv * sizeof(unsigned short)));
    long long chunk = cap > E ? E : cap;
    if (chunk < 1) chunk = 1;

    if (chunk >= E) {
        prep_kernel<<<4096, 256, 0, stream>>>(log_ev, log_cen, log_be, log_bc,
                                              tab, base_ev, base_ar, 0, E, 1);
        gather_kernel<<<B, 256, 0, stream>>>(sq_dists, labels, tab,
                                             base_ev, base_ar,
                                             acc_num, acc_den, out,
                                             K, 0, (int)E, 1);
    } else {
        hipMemsetAsync(acc_num, 0, 2 * (size_t)B * Dv * sizeof(float), stream);
        for (long long c0 = 0; c0 < E; c0 += chunk) {
            long long c1 = c0 + chunk; if (c1 > E) c1 = E;
            long long rows = c1 - c0;
            prep_kernel<<<4096, 256, 0, stream>>>(log_ev, log_cen, log_be, log_bc,
                                                  tab, base_ev, base_ar,
                                                  c0, rows, c0 == 0 ? 1 : 0);
            gather_kernel<<<B, 256, 0, stream>>>(sq_dists, labels, tab,
                                                 base_ev, base_ar,
                                                 acc_num, acc_den, out,
                                                 K, (int)c0, (int)c1, 0);
        }
        finalize_kernel<<<(B * Dv + 255) / 256, 256, 0, stream>>>(
            acc_num, acc_den, base_ev, base_ar, out, B * Dv);
    }
}

// Round 7
// 66.125 us; speedup vs baseline: 73.1627x; 73.1627x over previous
//
#include <hip/hip_runtime.h>
#include <hip/hip_fp16.h>
#include <math.h>

#define DD 128
#define TAU2 2.0f
#define EPSV 1e-12f

// Packet layout (16 B): packet j (j=0..31) of a row covers cols 4j..4j+3:
//   { half2(ev0,ev1), half2(ev2,ev3), half2(ar0,ar1), half2(ar2,ar3) }
// Row stride = 256 ushorts = 512 B.

// ---------------------------------------------------------------------------
// Prep: half-wave per row. Lane j (j = lane&31) owns cols 4j..4j+3 of row
// (halfwave id). float4 loads, 5-step shuffle suffix scan, one uint4 packet
// store per lane. Block 0 wave 0 also computes the baseline row.
// ---------------------------------------------------------------------------
__global__ __launch_bounds__(256) void prep_kernel(
    const float* __restrict__ log_ev,
    const float* __restrict__ log_cen,
    const float* __restrict__ log_be,
    const float* __restrict__ log_bc,
    unsigned short* __restrict__ tab,
    float* __restrict__ base_ev,
    float* __restrict__ base_ar,
    long long c0, long long rows, int do_base) {
    int tid = threadIdx.x;
    int lane = tid & 63;
    int j = lane & 31;           // packet index within row
    int h = lane >> 5;           // half of wave

    if (do_base && blockIdx.x == 0 && tid < 32) {
        float4 lb = *(const float4*)(log_be + 4 * j);
        float4 lc = *(const float4*)(log_bc + 4 * j);
        float e0 = __expf(lb.x), e1 = __expf(lb.y), e2 = __expf(lb.z), e3 = __expf(lb.w);
        float s0 = e0 + __expf(lc.x), s1 = e1 + __expf(lc.y);
        float s2 = e2 + __expf(lc.z), s3 = e3 + __expf(lc.w);
        float t = s0 + s1 + s2 + s3;
        #pragma unroll
        for (int off = 1; off < 32; off <<= 1) {
            float v = __shfl_down(t, off, 64);
            t += (j + off < 32) ? v : 0.0f;
        }
        *(float4*)(base_ev + 4 * j) = make_float4(e0, e1, e2, e3);
        *(float4*)(base_ar + 4 * j) = make_float4(t, t - s0, t - s0 - s1, t - s0 - s1 - s2);
    }

    long long g = (((long long)blockIdx.x * blockDim.x + tid) >> 6) * 2 + h;
    long long ng = (((long long)gridDim.x * blockDim.x) >> 6) * 2;

    for (long long row = g; row < rows; row += ng) {
        long long e = row + c0;
        size_t idx = (size_t)e * DD + 4 * j;
        float4 le = *(const float4*)(log_ev + idx);
        float4 lc = *(const float4*)(log_cen + idx);
        float e0 = __expf(le.x), e1 = __expf(le.y), e2 = __expf(le.z), e3 = __expf(le.w);
        float s0 = e0 + __expf(lc.x), s1 = e1 + __expf(lc.y);
        float s2 = e2 + __expf(lc.z), s3 = e3 + __expf(lc.w);
        float t = s0 + s1 + s2 + s3;
        #pragma unroll
        for (int off = 1; off < 32; off <<= 1) {
            float v = __shfl_down(t, off, 64);
            t += (j + off < 32) ? v : 0.0f;
        }
        __half2 ep0 = __floats2half2_rn(e0, e1);
        __half2 ep1 = __floats2half2_rn(e2, e3);
        __half2 ap0 = __floats2half2_rn(t, t - s0);
        __half2 ap1 = __floats2half2_rn(t - s0 - s1, t - s0 - s1 - s2);
        uint4 pkt;
        pkt.x = *(unsigned int*)&ep0;
        pkt.y = *(unsigned int*)&ep1;
        pkt.z = *(unsigned int*)&ap0;
        pkt.w = *(unsigned int*)&ap1;
        *(uint4*)(tab + (size_t)row * 256 + (size_t)j * 8) = pkt;
    }
}

// ---------------------------------------------------------------------------
// Gather: one block (256 threads = 4 waves) per output row b.
// Half-wave reads a full 512 B row (32 lanes x 16 B); wave covers 2 k's per
// step. Each lane accumulates 4 columns. 8 halfwave partials reduced via
// LDS; fused finalize (baseline add + divide + clip) writes out directly.
// ---------------------------------------------------------------------------
__global__ __launch_bounds__(256) void gather_kernel(
    const float* __restrict__ sq_dists,        // [B,K]
    const int*   __restrict__ labels,          // [B,K]
    const unsigned short* __restrict__ tab,    // [chunk][256] packed fp16
    const float* __restrict__ base_ev,         // [D]
    const float* __restrict__ base_ar,         // [D]
    float* __restrict__ acc_num,               // [B,D] (chunked path)
    float* __restrict__ acc_den,               // [B,D]
    float* __restrict__ out,                   // [B,D] (fused path)
    int K, int c0, int c1, int fused) {
    __shared__ float w_s[128];
    __shared__ int   lab_s[128];
    __shared__ float rn[8][DD];
    __shared__ float rd[8][DD];

    int b = blockIdx.x;
    int tid = threadIdx.x;
    if (tid < K) {
        float sqd = sq_dists[(size_t)b * K + tid];
        w_s[tid]  = (sqd <= TAU2) ? __expf(-sqd) : 0.0f;
        lab_s[tid] = labels[(size_t)b * K + tid];
    }
    __syncthreads();

    int wid = tid >> 6;
    int lane = tid & 63;
    int j = lane & 31;
    int h = lane >> 5;
    const unsigned short* jbase = tab + (size_t)j * 8;

    float n0 = 0.f, n1 = 0.f, n2 = 0.f, n3 = 0.f;
    float d0 = 0.f, d1 = 0.f, d2 = 0.f, d3 = 0.f;

    if (fused && K == 128) {
        int k0 = wid << 5;
        #pragma unroll
        for (int i = 0; i < 16; ++i) {
            int k = k0 + 2 * i + h;
            int l = lab_s[k];
            float wk = w_s[k];
            uint4 pkt = *(const uint4*)(jbase + (size_t)l * 256);
            float2 e01 = __half22float2(*(const __half2*)&pkt.x);
            float2 e23 = __half22float2(*(const __half2*)&pkt.y);
            float2 a01 = __half22float2(*(const __half2*)&pkt.z);
            float2 a23 = __half22float2(*(const __half2*)&pkt.w);
            n0 = fmaf(wk, e01.x, n0); n1 = fmaf(wk, e01.y, n1);
            n2 = fmaf(wk, e23.x, n2); n3 = fmaf(wk, e23.y, n3);
            d0 = fmaf(wk, a01.x, d0); d1 = fmaf(wk, a01.y, d1);
            d2 = fmaf(wk, a23.x, d2); d3 = fmaf(wk, a23.y, d3);
        }
    } else {
        int kpw = (K + 3) >> 2;
        for (int kk = h; kk < kpw; kk += 2) {
            int k = wid * kpw + kk;
            if (k >= K) break;
            int l = lab_s[k];
            if (l >= c0 && l < c1) {
                float wk = w_s[k];
                uint4 pkt = *(const uint4*)(jbase + (size_t)(l - c0) * 256);
                float2 e01 = __half22float2(*(const __half2*)&pkt.x);
                float2 e23 = __half22float2(*(const __half2*)&pkt.y);
                float2 a01 = __half22float2(*(const __half2*)&pkt.z);
                float2 a23 = __half22float2(*(const __half2*)&pkt.w);
                n0 = fmaf(wk, e01.x, n0); n1 = fmaf(wk, e01.y, n1);
                n2 = fmaf(wk, e23.x, n2); n3 = fmaf(wk, e23.y, n3);
                d0 = fmaf(wk, a01.x, d0); d1 = fmaf(wk, a01.y, d1);
                d2 = fmaf(wk, a23.x, d2); d3 = fmaf(wk, a23.y, d3);
            }
        }
    }
    int part = wid * 2 + h;
    *(float4*)&rn[part][4 * j] = make_float4(n0, n1, n2, n3);
    *(float4*)&rd[part][4 * j] = make_float4(d0, d1, d2, d3);
    __syncthreads();

    if (tid < DD) {
        float n  = rn[0][tid] + rn[1][tid] + rn[2][tid] + rn[3][tid]
                 + rn[4][tid] + rn[5][tid] + rn[6][tid] + rn[7][tid];
        float dn = rd[0][tid] + rd[1][tid] + rd[2][tid] + rd[3][tid]
                 + rd[4][tid] + rd[5][tid] + rd[6][tid] + rd[7][tid];
        size_t o = (size_t)b * DD + tid;
        if (fused) {
            n  += base_ev[tid];
            dn += base_ar[tid] + EPSV;
            float r = n / dn;
            out[o] = fminf(fmaxf(r, EPSV), 1.0f - EPSV);
        } else {
            acc_num[o] += n;
            acc_den[o] += dn;
        }
    }
}

// ---------------------------------------------------------------------------
// Finalize (chunked fallback only)
// ---------------------------------------------------------------------------
__global__ void finalize_kernel(const float* __restrict__ acc_num,
                                const float* __restrict__ acc_den,
                                const float* __restrict__ base_ev,
                                const float* __restrict__ base_ar,
                                float* __restrict__ out, int total) {
    int i = blockIdx.x * blockDim.x + threadIdx.x;
    if (i >= total) return;
    int d = i & (DD - 1);
    float n  = acc_num[i] + base_ev[d];
    float dn = acc_den[i] + base_ar[d] + EPSV;
    float r = n / dn;
    r = fminf(fmaxf(r, EPSV), 1.0f - EPSV);
    out[i] = r;
}

extern "C" void kernel_launch(void* const* d_in, const int* in_sizes, int n_in,
                              void* d_out, int out_size, void* d_ws, size_t ws_size,
                              hipStream_t stream) {
    const float* sq_dists = (const float*)d_in[0];
    const float* log_ev   = (const float*)d_in[1];
    const float* log_cen  = (const float*)d_in[2];
    const float* log_be   = (const float*)d_in[3];
    const float* log_bc   = (const float*)d_in[4];
    const int*   labels   = (const int*)d_in[5];
    float* out = (float*)d_out;

    const int Dv = in_sizes[3];                        // 128
    const long long E = (long long)in_sizes[1] / Dv;   // 100000
    const int B = out_size / Dv;                       // 4096
    const int K = in_sizes[0] / B;                     // 128

    // ws layout: [acc_num B*D][acc_den B*D][base_ev D][base_ar D][table ...]
    float* ws = (float*)d_ws;
    float* acc_num = ws;
    float* acc_den = acc_num + (size_t)B * Dv;
    float* base_ev = acc_den + (size_t)B * Dv;
    float* base_ar = base_ev + Dv;
    size_t head_floats = 2 * (size_t)B * Dv + 2 * (size_t)Dv;
    unsigned short* tab = (unsigned short*)(ws + head_floats);

    size_t head_bytes = head_floats * sizeof(float);
    long long cap = 0;
    if (ws_size > head_bytes)
        cap = (long long)((ws_size - head_bytes) / (2 * (size_t)Dv * sizeof(unsigned short)));
    long long chunk = cap > E ? E : cap;
    if (chunk < 1) chunk = 1;

    if (chunk >= E) {
        prep_kernel<<<4096, 256, 0, stream>>>(log_ev, log_cen, log_be, log_bc,
                                              tab, base_ev, base_ar, 0, E, 1);
        gather_kernel<<<B, 256, 0, stream>>>(sq_dists, labels, tab,
                                             base_ev, base_ar,
                                             acc_num, acc_den, out,
                                             K, 0, (int)E, 1);
    } else {
        hipMemsetAsync(acc_num, 0, 2 * (size_t)B * Dv * sizeof(float), stream);
        for (long long c0 = 0; c0 < E; c0 += chunk) {
            long long c1 = c0 + chunk; if (c1 > E) c1 = E;
            long long rows = c1 - c0;
            prep_kernel<<<4096, 256, 0, stream>>>(log_ev, log_cen, log_be, log_bc,
                                                  tab, base_ev, base_ar,
                                                  c0, rows, c0 == 0 ? 1 : 0);
            gather_kernel<<<B, 256, 0, stream>>>(sq_dists, labels, tab,
                                                 base_ev, base_ar,
                                                 acc_num, acc_den, out,
                                                 K, (int)c0, (int)c1, 0);
        }
        finalize_kernel<<<(B * Dv + 255) / 256, 256, 0, stream>>>(
            acc_num, acc_den, base_ev, base_ar, out, B * Dv);
    }
}